// Round 1
// baseline (535.411 us; speedup 1.0000x reference)
//
#include <hip/hip_runtime.h>
#include <hip/hip_bf16.h>

#define AST_DIM 256
#define NR_AST 500000
#define NR_CFG 100000
#define NR_MAP 400000

typedef short short8 __attribute__((ext_vector_type(8)));
typedef float f32x4 __attribute__((ext_vector_type(4)));

__device__ __forceinline__ unsigned short f2bf(float f) {
    unsigned int u = __float_as_uint(f);
    u += 0x7FFFu + ((u >> 16) & 1u);   // round-to-nearest-even
    return (unsigned short)(u >> 16);
}
__device__ __forceinline__ float bf2f(unsigned short s) {
    return __uint_as_float(((unsigned int)s) << 16);
}
__device__ __forceinline__ unsigned long long pack4(float4 v) {
    unsigned long long lo = (unsigned long long)f2bf(v.x) | ((unsigned long long)f2bf(v.y) << 16);
    unsigned long long hi = (unsigned long long)f2bf(v.z) | ((unsigned long long)f2bf(v.w) << 16);
    return lo | (hi << 32);
}
__device__ __forceinline__ float fast_tanh(float x) {
    return 1.f - 2.f * __builtin_amdgcn_rcpf(__expf(2.f * x) + 1.f);
}
__device__ __forceinline__ float fast_sigmoid(float x) {
    return __builtin_amdgcn_rcpf(1.f + __expf(-x));
}

// Convert W_update / W_gate (f32, [K][N]) to bf16 TRANSPOSED [N][K] so MFMA
// B-fragments (8 consecutive k at fixed n) are contiguous 16B loads.
// Layout in ws: [0]=Wt_update, [1]=Wt_gate_top (k<256), [2]=Wt_gate_bot.
__global__ void convert_w(const float* __restrict__ Wu, const float* __restrict__ Wg,
                          unsigned short* __restrict__ wt) {
    int idx = blockIdx.x * 256 + threadIdx.x;
    if (idx >= 3 * 65536) return;
    int m = idx >> 16;
    int r = idx & 65535;
    int n = r >> 8;
    int k = r & 255;
    float v;
    if (m == 0)      v = Wu[k * 256 + n];
    else if (m == 1) v = Wg[k * 256 + n];
    else             v = Wg[(k + 256) * 256 + n];
    wt[idx] = f2bf(v);
}

__global__ void set_mask(const int* __restrict__ keys, unsigned char* __restrict__ mask) {
    int i = blockIdx.x * 256 + threadIdx.x;
    if (i < NR_MAP) mask[keys[i]] = 1;
}

// Copy only the UNMAPPED rows (20%); mapped rows are written by mixer_main.
__global__ void copy_unmapped(const float* __restrict__ prev,
                              const unsigned char* __restrict__ mask,
                              float* __restrict__ out) {
    const long long total = (long long)NR_AST * 64;  // float4 units
    for (long long i = (long long)blockIdx.x * blockDim.x + threadIdx.x; i < total;
         i += (long long)gridDim.x * blockDim.x) {
        int row = (int)(i >> 6);
        if (!mask[row])  // wave-uniform: 64 consecutive lanes share a row
            ((float4*)out)[i] = ((const float4*)prev)[i];
    }
}

// Main kernel: 512 threads (8 waves), 64 mapped rows per block.
// Wave w owns output columns [w*32, w*32+32).
// LDS: ctx tile (reused for u after GEMM1) + prev tile, both bf16 [64][256],
// XOR-swizzled (row stride 512B would otherwise be a 16-way bank conflict).
__global__ __launch_bounds__(512, 4) void mixer_main(
    const float* __restrict__ prev, const float* __restrict__ cfg,
    const int* __restrict__ keys, const int* __restrict__ vals,
    const unsigned short* __restrict__ Wtu, const unsigned short* __restrict__ Wtgt,
    const unsigned short* __restrict__ Wtgb, const float* __restrict__ bu,
    const float* __restrict__ bg, float* __restrict__ out) {
    __shared__ __align__(16) unsigned char ctx_lds[64 * 512];  // ctx, then u
    __shared__ __align__(16) unsigned char prv_lds[64 * 512];
    __shared__ int skey[64];
    __shared__ int sval[64];

    const int tid = threadIdx.x;
    const int lane = tid & 63;
    const int wave = tid >> 6;  // 0..7
    const int ln15 = lane & 15;
    const int khi = lane >> 4;  // 0..3
    const int m0 = blockIdx.x * 64;

    if (tid < 64) skey[tid] = keys[m0 + tid];
    else if (tid < 128) sval[tid - 64] = vals[m0 + (tid - 64)];
    __syncthreads();

    // ---- stage: gather 64 ctx rows + 64 prev rows, f32 -> bf16 -> LDS ----
    // one row = 64 lanes * float4 (1KB contiguous global read)
#pragma unroll 4
    for (int i = 0; i < 8; ++i) {
        int r = i * 8 + wave;
        float4 cv = *((const float4*)(cfg + (size_t)sval[r] * AST_DIM) + lane);
        float4 pv = *((const float4*)(prev + (size_t)skey[r] * AST_DIM) + lane);
        int addr = (r << 9) + (lane << 3);
        addr ^= (r & 7) << 4;  // XOR swizzle, 16B granularity
        *(unsigned long long*)(ctx_lds + addr) = pack4(cv);
        *(unsigned long long*)(prv_lds + addr) = pack4(pv);
    }
    __syncthreads();

    const int cb = wave * 32;  // column base of this wave

    // ---- GEMM1: u_pre = ctx @ W_update + b_update ----
    f32x4 acc[4][2];
    for (int nt = 0; nt < 2; ++nt) {
        float b = bu[cb + nt * 16 + ln15];
        f32x4 bv = {b, b, b, b};
        for (int mt = 0; mt < 4; ++mt) acc[mt][nt] = bv;
    }
#pragma unroll
    for (int ks = 0; ks < 8; ++ks) {
        short8 a[4], b[2];
        for (int mt = 0; mt < 4; ++mt) {
            int row = mt * 16 + ln15;
            int addr = (row << 9) + (ks << 6) + (khi << 4);
            addr ^= (row & 7) << 4;
            a[mt] = *(const short8*)(ctx_lds + addr);
        }
        for (int nt = 0; nt < 2; ++nt) {
            int col = cb + nt * 16 + ln15;
            b[nt] = *(const short8*)(Wtu + col * 256 + ks * 32 + khi * 8);
        }
        for (int mt = 0; mt < 4; ++mt)
            for (int nt = 0; nt < 2; ++nt)
                acc[mt][nt] = __builtin_amdgcn_mfma_f32_16x16x32_bf16(a[mt], b[nt], acc[mt][nt], 0, 0, 0);
    }
    __syncthreads();  // all waves done reading ctx tile

    // ---- tanh; write u (bf16) into ctx_lds region (aliased) ----
#pragma unroll
    for (int mt = 0; mt < 4; ++mt)
        for (int nt = 0; nt < 2; ++nt)
            for (int r = 0; r < 4; ++r) {
                float uv = fast_tanh(acc[mt][nt][r]);
                int row = mt * 16 + khi * 4 + r;   // C/D layout: row=(lane>>4)*4+reg
                int col = cb + nt * 16 + ln15;     //             col=lane&15
                int addr = (row << 9) + (col << 1);
                addr ^= (row & 7) << 4;
                *(unsigned short*)(ctx_lds + addr) = f2bf(uv);
            }
    __syncthreads();

    // ---- GEMM2: z_pre = prev @ Wg_top + u @ Wg_bot + b_gate ----
    for (int nt = 0; nt < 2; ++nt) {
        float b = bg[cb + nt * 16 + ln15];
        f32x4 bv = {b, b, b, b};
        for (int mt = 0; mt < 4; ++mt) acc[mt][nt] = bv;
    }
#pragma unroll
    for (int ks = 0; ks < 8; ++ks) {
        short8 a[4], b[2];
        for (int mt = 0; mt < 4; ++mt) {
            int row = mt * 16 + ln15;
            int addr = (row << 9) + (ks << 6) + (khi << 4);
            addr ^= (row & 7) << 4;
            a[mt] = *(const short8*)(prv_lds + addr);
        }
        for (int nt = 0; nt < 2; ++nt) {
            int col = cb + nt * 16 + ln15;
            b[nt] = *(const short8*)(Wtgt + col * 256 + ks * 32 + khi * 8);
        }
        for (int mt = 0; mt < 4; ++mt)
            for (int nt = 0; nt < 2; ++nt)
                acc[mt][nt] = __builtin_amdgcn_mfma_f32_16x16x32_bf16(a[mt], b[nt], acc[mt][nt], 0, 0, 0);
    }
#pragma unroll
    for (int ks = 0; ks < 8; ++ks) {
        short8 a[4], b[2];
        for (int mt = 0; mt < 4; ++mt) {
            int row = mt * 16 + ln15;
            int addr = (row << 9) + (ks << 6) + (khi << 4);
            addr ^= (row & 7) << 4;
            a[mt] = *(const short8*)(ctx_lds + addr);  // u
        }
        for (int nt = 0; nt < 2; ++nt) {
            int col = cb + nt * 16 + ln15;
            b[nt] = *(const short8*)(Wtgb + col * 256 + ks * 32 + khi * 8);
        }
        for (int mt = 0; mt < 4; ++mt)
            for (int nt = 0; nt < 2; ++nt)
                acc[mt][nt] = __builtin_amdgcn_mfma_f32_16x16x32_bf16(a[mt], b[nt], acc[mt][nt], 0, 0, 0);
    }

    // ---- epilogue: z = sigmoid, blend, scatter-store ----
#pragma unroll
    for (int mt = 0; mt < 4; ++mt)
        for (int nt = 0; nt < 2; ++nt)
            for (int r = 0; r < 4; ++r) {
                float z = fast_sigmoid(acc[mt][nt][r]);
                int row = mt * 16 + khi * 4 + r;
                int col = cb + nt * 16 + ln15;
                int ad = (row << 9) + (col << 1);
                ad ^= (row & 7) << 4;
                float pf = bf2f(*(const unsigned short*)(prv_lds + ad));
                float uv = bf2f(*(const unsigned short*)(ctx_lds + ad));
                float nv = fmaf(z, pf - uv, uv);  // z*prev + (1-z)*u
                out[(size_t)skey[row] * AST_DIM + col] = nv;  // 16 lanes = 64B contiguous
            }
}

extern "C" void kernel_launch(void* const* d_in, const int* in_sizes, int n_in,
                              void* d_out, int out_size, void* d_ws, size_t ws_size,
                              hipStream_t stream) {
    const float* prev = (const float*)d_in[0];
    const float* cfg = (const float*)d_in[1];
    const int* keys = (const int*)d_in[2];
    const int* vals = (const int*)d_in[3];
    const float* Wu = (const float*)d_in[4];
    const float* bu = (const float*)d_in[5];
    const float* Wg = (const float*)d_in[6];
    const float* bg = (const float*)d_in[7];
    float* out = (float*)d_out;

    unsigned short* wt = (unsigned short*)d_ws;                    // 3*65536 bf16 = 384KB
    unsigned char* mask = (unsigned char*)d_ws + 3 * 65536 * 2;    // NR_AST bytes

    hipMemsetAsync(mask, 0, NR_AST, stream);
    convert_w<<<768, 256, 0, stream>>>(Wu, Wg, wt);
    set_mask<<<(NR_MAP + 255) / 256, 256, 0, stream>>>(keys, mask);
    copy_unmapped<<<2048, 256, 0, stream>>>(prev, mask, out);
    mixer_main<<<NR_MAP / 64, 512, 0, stream>>>(prev, cfg, keys, vals, wt, wt + 65536,
                                                wt + 2 * 65536, bu, bg, out);
}